// Round 3
// baseline (143.118 us; speedup 1.0000x reference)
//
#include <hip/hip_runtime.h>
#include <math.h>

typedef _Float16 half8  __attribute__((ext_vector_type(8)));
typedef _Float16 half4v __attribute__((ext_vector_type(4)));
typedef float    floatx4 __attribute__((ext_vector_type(4)));

#define DDIM 256

// async global->LDS, 16B per lane; LDS dest = wave-uniform base + lane*16
#define GLOAD_LDS16(g, l) \
    __builtin_amdgcn_global_load_lds((const __attribute__((address_space(1))) void*)(g), \
                                     (__attribute__((address_space(3))) void*)(l), 16, 0, 0)

// ------------------------------------------------------------ fused prep
// blocks [0,2048): fp32->fp16 convert of q (first 1024) and t (next 1024)
// blocks [2048,2080): per-token vMF stats, ONE TOKEN PER THREAD (8192 tokens).
__global__ void prep(const float* __restrict__ q, const float* __restrict__ t,
                     _Float16* __restrict__ Qh, _Float16* __restrict__ Th,
                     const float* __restrict__ kq, const float* __restrict__ kt,
                     float* __restrict__ Apq, float* __restrict__ kqc, float* __restrict__ uq,
                     float* __restrict__ wq,
                     float* __restrict__ At,  float* __restrict__ ktc, float* __restrict__ vt,
                     float* __restrict__ ent_out, int* __restrict__ counter) {
    int b = blockIdx.x;
    if (b < 2048) {
        const float* src = (b < 1024) ? q : t;
        _Float16*    dst = (b < 1024) ? Qh : Th;
        int i = ((b & 1023) * 1024) + threadIdx.x * 4;
        float4 v = *(const float4*)(src + i);
        half4v h;
        h[0] = (_Float16)v.x; h[1] = (_Float16)v.y; h[2] = (_Float16)v.z; h[3] = (_Float16)v.w;
        *(half4v*)(dst + i) = h;
        return;
    }

    __shared__ float slg_s[50];    // lgamma(k+1)+lgamma(k+128)
    __shared__ float l128_s[50];   // log(k+128)
    int tid = threadIdx.x;

    if (b == 2048 && tid == 0) counter[0] = 0;   // gemm last-block gate (ws is re-poisoned)

    // build tables with wave 0 (identical numerics to previous rounds:
    // lgamma(k+1)+lgamma(k+128) = lgamma(128) + prefix_sum[log j + log(j+127)])
    if (tid < 64) {
        int lane = tid;
        float a = 0.f;
        if (lane >= 1 && lane < 50) a = logf((float)lane) + logf((float)(lane + 127));
        #pragma unroll
        for (int off = 1; off < 64; off <<= 1) {
            float tmp = __shfl_up(a, off, 64);
            if (lane >= off) a += tmp;
        }
        if (lane < 50) {
            slg_s[lane]  = 491.5534482233f + a;
            l128_s[lane] = logf((float)(lane + 128));
        }
    }
    __syncthreads();

    int tok  = (b - 2048) * 256 + tid;          // 0..8191
    bool isQ = tok < 4096;
    float kap  = fmaxf(isQ ? kq[tok] : kt[tok - 4096], 1e-6f);
    float lkap = logf(kap);
    float lx   = lkap - 0.6931471805599453f;    // log(kap/2)

    // pass 1: maxes of the two log-coef series (I_127 and I_128)
    float m0 = -INFINITY, m1 = -INFINITY;
    #pragma unroll 10
    for (int k = 0; k < 50; ++k) {
        float c0 = fmaf((float)(2 * k + 127), lx, -slg_s[k]);
        float c1 = c0 + lx - l128_s[k];
        m0 = fmaxf(m0, c0);
        m1 = fmaxf(m1, c1);
    }
    // pass 2: exp-accumulate
    float s0 = 0.f, s1 = 0.f;
    #pragma unroll 10
    for (int k = 0; k < 50; ++k) {
        float c0 = fmaf((float)(2 * k + 127), lx, -slg_s[k]);
        float c1 = c0 + lx - l128_s[k];
        s0 += expf(c0 - m0);
        s1 += expf(c1 - m1);
    }
    float logI0 = m0 + logf(s0);   // log I_127(kap)
    float logI1 = m1 + logf(s1);   // log I_128(kap)

    float A = expf(fminf(fmaxf(logI1 - logI0, -60.f), 0.f));
    A = fminf(fmaxf(A, 1e-8f), 1.f - 1e-6f);
    float logC = 127.f * lkap - 235.2482644983962f - logI0;  // 128*log(2pi)
    float ent  = -logC - kap * A;

    if (isQ) {
        // softmax of -2*ent over each row's 32 tokens; rows are 32-lane aligned
        float x = -2.0f * ent;
        float m = x;
        #pragma unroll
        for (int off = 1; off < 32; off <<= 1) m = fmaxf(m, __shfl_xor(m, off, 64));
        float p = expf(x - m);
        float s = p;
        #pragma unroll
        for (int off = 1; off < 32; off <<= 1) s += __shfl_xor(s, off, 64);
        Apq[tok] = A; kqc[tok] = kap; uq[tok] = -0.5f * A * kap;
        wq[tok]  = p / s;
        ent_out[tok] = ent;
    } else {
        int tt = tok - 4096;
        At[tt] = A; ktc[tt] = kap; vt[tt] = -0.5f * A * kap;
    }
}

// --------------------------------------------------- fused GEMM + vMF epilogue
// 256x256 tile/block, 8 waves in 2x4 quadrants, 8x4 grid of 16x16x32 f16 MFMA.
// 1D grid of 256 blocks with XCD-chunked swizzle (T1): XCD g owns a 4(bx)x8(by)
// rectangle -> per-XCD panel working set 6 MB (vs 16 MB round-robin), so Q/T
// panel re-reads hit the XCD's 4 MiB L2. LDS 128 KB, double-buffered staging,
// one barrier per K-chunk, XOR chunk swizzle for bank-spread ds_read_b128.
// TAIL FUSION: last block to finish (device-scope counter, agent-scope fences
// per G16 for cross-XCD visibility) runs the row-softmax + loss, eliminating
// the separate softmax_loss kernel and its launch gap.
__global__ void __launch_bounds__(512, 2)
gemm_score(const _Float16* __restrict__ Qh, const _Float16* __restrict__ Th,
           const float* __restrict__ Apq, const float* __restrict__ kqc,
           const float* __restrict__ uq,  const float* __restrict__ wq,
           const float* __restrict__ At,  const float* __restrict__ ktc,
           const float* __restrict__ vt,  float* __restrict__ score_out,
           const float* __restrict__ temp_p, float* __restrict__ logits,
           float* __restrict__ loss, int* __restrict__ counter) {
    __shared__ _Float16 Qs[2][256 * 64];   // 2 x 32 KB
    __shared__ _Float16 Ts[2][256 * 64];
    int tid = threadIdx.x;
    int lane = tid & 63, wave = tid >> 6;   // 8 waves
    int wr = wave >> 2, wc = wave & 3;      // 2 (M) x 4 (N)

    // XCD-chunked bijective swizzle: g = bid&7 -> 4x8 rectangle of the 16x16 grid
    int bid = blockIdx.x;
    int g = bid & 7, ii_ = bid >> 3;
    int bx = (g & 3) * 4 + (ii_ & 3);
    int by = (g >> 2) * 8 + (ii_ >> 2);

    floatx4 acc[8][4];
    #pragma unroll
    for (int i = 0; i < 8; ++i)
        #pragma unroll
        for (int j = 0; j < 4; ++j)
            acc[i][j] = (floatx4){0.f, 0.f, 0.f, 0.f};

    int l15 = lane & 15, lq = lane >> 4;
    int swz = l15 & 7;

    // staging: thread covers row rs (+it*64), LDS chunk cl, global chunk cg
    int rs = tid >> 3;                      // 0..63
    int cl = tid & 7;
    int cg = cl ^ (rs & 7);
    const _Float16* gq = Qh + (size_t)(by * 256 + rs) * DDIM + cg * 8;
    const _Float16* gt = Th + (size_t)(bx * 256 + rs) * DDIM + cg * 8;
    int lbase = wave * 1024;                // LDS byte base (+it*8192)

    // prologue: chunk 0 -> buffer 0 (only exposed staging wait in the kernel)
    #pragma unroll
    for (int it = 0; it < 4; ++it) {
        GLOAD_LDS16(gq + it * 64 * DDIM, (char*)Qs[0] + lbase + it * 8192);
        GLOAD_LDS16(gt + it * 64 * DDIM, (char*)Ts[0] + lbase + it * 8192);
    }

    #pragma unroll
    for (int kk = 0; kk < 4; ++kk) {
        int p = kk & 1;
        // drains: chunk-kk loads (issued one iteration ago) + last ds_reads
        __syncthreads();
        if (kk < 3) {                       // prefetch chunk kk+1 into other buf
            #pragma unroll
            for (int it = 0; it < 4; ++it) {
                GLOAD_LDS16(gq + it * 64 * DDIM + (kk + 1) * 64,
                            (char*)Qs[p ^ 1] + lbase + it * 8192);
                GLOAD_LDS16(gt + it * 64 * DDIM + (kk + 1) * 64,
                            (char*)Ts[p ^ 1] + lbase + it * 8192);
            }
        }
        #pragma unroll
        for (int ks = 0; ks < 2; ++ks) {
            half8 a[8], b[4];
            int chunk = (ks * 4 + lq) ^ swz;
            #pragma unroll
            for (int i = 0; i < 8; ++i)
                a[i] = *(const half8*)(Qs[p] + (wr * 128 + i * 16 + l15) * 64 + chunk * 8);
            #pragma unroll
            for (int j = 0; j < 4; ++j)
                b[j] = *(const half8*)(Ts[p] + (wc * 64 + j * 16 + l15) * 64 + chunk * 8);
            #pragma unroll
            for (int i = 0; i < 8; ++i)
                #pragma unroll
                for (int j = 0; j < 4; ++j)
                    acc[i][j] = __builtin_amdgcn_mfma_f32_16x16x32_f16(a[i], b[j], acc[i][j], 0, 0, 0);
        }
    }

    // ---- epilogue: max over 32 t-cols, weighted sum over 32 q-rows
    int colbase = bx * 256 + wc * 64 + l15;
    int rowbase = by * 256 + wr * 128 + lq * 4;
    #pragma unroll
    for (int bi = 0; bi < 4; ++bi) {         // 4 samples per wave (32 rows each)
        #pragma unroll
        for (int bj = 0; bj < 2; ++bj) {     // 2 targets per wave (32 cols each)
            float part = 0.f;
            #pragma unroll
            for (int ii2 = 0; ii2 < 2; ++ii2) {
                int i  = bi * 2 + ii2;
                int rg = rowbase + i * 16;
                float mx[4] = {-INFINITY, -INFINITY, -INFINITY, -INFINITY};
                #pragma unroll
                for (int jj = 0; jj < 2; ++jj) {
                    int j   = bj * 2 + jj;
                    int cg2 = colbase + j * 16;
                    float at_ = At[cg2], kt_ = ktc[cg2], v_ = vt[cg2];
                    floatx4 sim = acc[i][j];
                    #pragma unroll
                    for (int rr = 0; rr < 4; ++rr) {
                        float sc = uq[rg + rr] + v_ +
                                   0.5f * (Apq[rg + rr] * kt_ + at_ * kqc[rg + rr]) * sim[rr];
                        mx[rr] = fmaxf(mx[rr], sc);
                    }
                }
                #pragma unroll
                for (int msk = 1; msk <= 8; msk <<= 1)
                    #pragma unroll
                    for (int rr = 0; rr < 4; ++rr)
                        mx[rr] = fmaxf(mx[rr], __shfl_xor(mx[rr], msk, 64));
                if (l15 == 0) {
                    #pragma unroll
                    for (int rr = 0; rr < 4; ++rr)
                        part += wq[rg + rr] * mx[rr];
                }
            }
            part += __shfl_xor(part, 16, 64);
            part += __shfl_xor(part, 32, 64);
            if (lane == 0) {
                int b = by * 8 + wr * 4 + bi;
                int n = bx * 8 + wc * 2 + bj;
                score_out[b * 128 + n] = part;
            }
        }
    }

    // ---- last-block tail: row-softmax over n, logits, loss
    __shared__ int lastFlag;
    __shared__ float lpart[8];
    __threadfence();                         // release: write back our score stores
    if (tid == 0) {
        int old = atomicAdd(counter, 1);     // device-scope
        lastFlag = (old == 255);
    }
    __syncthreads();
    if (!lastFlag) return;
    __threadfence();                         // acquire: invalidate so we see all XCDs' scores

    float temp = fmaxf(temp_p[0], 1e-6f);
    float inv = 1.0f / temp;
    float lsum = 0.f;
    for (int rr = 0; rr < 16; ++rr) {        // 8 waves x 16 rows = 128 rows
        int r = wave * 16 + rr;
        float2 v = ((const float2*)(score_out + r * 128))[lane];
        v.x *= inv; v.y *= inv;
        float m = fmaxf(v.x, v.y);
        #pragma unroll
        for (int off = 1; off < 64; off <<= 1) m = fmaxf(m, __shfl_xor(m, off, 64));
        float e = expf(v.x - m) + expf(v.y - m);
        #pragma unroll
        for (int off = 1; off < 64; off <<= 1) e += __shfl_xor(e, off, 64);
        float lse = m + logf(e);
        ((float2*)(logits + r * 128))[lane] = v;
        if (lane == 0) lsum += lse - score_out[r * 129] * inv;   // diag
    }
    if (lane == 0) lpart[wave] = lsum;
    __syncthreads();
    if (tid == 0) {
        float s = 0.f;
        #pragma unroll
        for (int i = 0; i < 8; ++i) s += lpart[i];
        loss[0] = s * (1.0f / 128.0f);
    }
}

// ---------------------------------------------------------------------- launch
extern "C" void kernel_launch(void* const* d_in, const int* in_sizes, int n_in,
                              void* d_out, int out_size, void* d_ws, size_t ws_size,
                              hipStream_t stream) {
    const float* q    = (const float*)d_in[0];   // (128,32,256)
    const float* kq   = (const float*)d_in[1];   // (128,32)
    const float* t    = (const float*)d_in[2];   // (128,32,256)
    const float* kt   = (const float*)d_in[3];   // (128,32)
    const float* temp = (const float*)d_in[4];   // scalar

    float* out    = (float*)d_out;
    float* loss   = out;                 // [1]
    float* logits = out + 1;             // [128*128]
    float* score  = out + 1 + 16384;     // [128*128]
    float* ent    = out + 1 + 32768;     // [128*32]

    char* ws = (char*)d_ws;
    _Float16* Qh = (_Float16*)(ws);
    _Float16* Th = (_Float16*)(ws + (1 << 21));
    float* stats = (float*)(ws + (1 << 22));
    float *Apq = stats,          *kqc = stats + 4096, *uq = stats + 8192,
          *wq  = stats + 12288,  *At  = stats + 16384, *ktc = stats + 20480,
          *vt  = stats + 24576;
    int* counter = (int*)(stats + 28672);

    prep<<<2080, 256, 0, stream>>>(q, t, Qh, Th, kq, kt,
                                   Apq, kqc, uq, wq, At, ktc, vt, ent, counter);
    gemm_score<<<256, 512, 0, stream>>>(Qh, Th, Apq, kqc, uq, wq, At, ktc, vt, score,
                                        temp, logits, loss, counter);
}

// Round 4
// 99.468 us; speedup vs baseline: 1.4388x; 1.4388x over previous
//
#include <hip/hip_runtime.h>
#include <math.h>

typedef _Float16 half8  __attribute__((ext_vector_type(8)));
typedef _Float16 half4v __attribute__((ext_vector_type(4)));
typedef float    floatx4 __attribute__((ext_vector_type(4)));

#define DDIM 256

// async global->LDS, 16B per lane; LDS dest = wave-uniform base + lane*16
#define GLOAD_LDS16(g, l) \
    __builtin_amdgcn_global_load_lds((const __attribute__((address_space(1))) void*)(g), \
                                     (__attribute__((address_space(3))) void*)(l), 16, 0, 0)

// ------------------------------------------------------------ fused prep
// blocks [0,2048): fp32->fp16 convert of q (first 1024) and t (next 1024)
// blocks [2048,2080): per-token vMF stats, ONE TOKEN PER THREAD (8192 tokens).
__global__ void prep(const float* __restrict__ q, const float* __restrict__ t,
                     _Float16* __restrict__ Qh, _Float16* __restrict__ Th,
                     const float* __restrict__ kq, const float* __restrict__ kt,
                     float* __restrict__ Apq, float* __restrict__ kqc, float* __restrict__ uq,
                     float* __restrict__ wq,
                     float* __restrict__ At,  float* __restrict__ ktc, float* __restrict__ vt,
                     float* __restrict__ ent_out, float* __restrict__ loss) {
    int b = blockIdx.x;
    if (b < 2048) {
        const float* src = (b < 1024) ? q : t;
        _Float16*    dst = (b < 1024) ? Qh : Th;
        int i = ((b & 1023) * 1024) + threadIdx.x * 4;
        float4 v = *(const float4*)(src + i);
        half4v h;
        h[0] = (_Float16)v.x; h[1] = (_Float16)v.y; h[2] = (_Float16)v.z; h[3] = (_Float16)v.w;
        *(half4v*)(dst + i) = h;
        return;
    }

    __shared__ float slg_s[50];    // lgamma(k+1)+lgamma(k+128)
    __shared__ float l128_s[50];   // log(k+128)
    int tid = threadIdx.x;

    if (b == 2048 && tid == 0) loss[0] = 0.f;   // softmax_loss accumulates here

    // build tables with wave 0 (identical numerics to previous rounds:
    // lgamma(k+1)+lgamma(k+128) = lgamma(128) + prefix_sum[log j + log(j+127)])
    if (tid < 64) {
        int lane = tid;
        float a = 0.f;
        if (lane >= 1 && lane < 50) a = logf((float)lane) + logf((float)(lane + 127));
        #pragma unroll
        for (int off = 1; off < 64; off <<= 1) {
            float tmp = __shfl_up(a, off, 64);
            if (lane >= off) a += tmp;
        }
        if (lane < 50) {
            slg_s[lane]  = 491.5534482233f + a;
            l128_s[lane] = logf((float)(lane + 128));
        }
    }
    __syncthreads();

    int tok  = (b - 2048) * 256 + tid;          // 0..8191
    bool isQ = tok < 4096;
    float kap  = fmaxf(isQ ? kq[tok] : kt[tok - 4096], 1e-6f);
    float lkap = logf(kap);
    float lx   = lkap - 0.6931471805599453f;    // log(kap/2)

    // pass 1: maxes of the two log-coef series (I_127 and I_128)
    float m0 = -INFINITY, m1 = -INFINITY;
    #pragma unroll 10
    for (int k = 0; k < 50; ++k) {
        float c0 = fmaf((float)(2 * k + 127), lx, -slg_s[k]);
        float c1 = c0 + lx - l128_s[k];
        m0 = fmaxf(m0, c0);
        m1 = fmaxf(m1, c1);
    }
    // pass 2: exp-accumulate
    float s0 = 0.f, s1 = 0.f;
    #pragma unroll 10
    for (int k = 0; k < 50; ++k) {
        float c0 = fmaf((float)(2 * k + 127), lx, -slg_s[k]);
        float c1 = c0 + lx - l128_s[k];
        s0 += expf(c0 - m0);
        s1 += expf(c1 - m1);
    }
    float logI0 = m0 + logf(s0);   // log I_127(kap)
    float logI1 = m1 + logf(s1);   // log I_128(kap)

    float A = expf(fminf(fmaxf(logI1 - logI0, -60.f), 0.f));
    A = fminf(fmaxf(A, 1e-8f), 1.f - 1e-6f);
    float logC = 127.f * lkap - 235.2482644983962f - logI0;  // 128*log(2pi)
    float ent  = -logC - kap * A;

    if (isQ) {
        // softmax of -2*ent over each row's 32 tokens; rows are 32-lane aligned
        float x = -2.0f * ent;
        float m = x;
        #pragma unroll
        for (int off = 1; off < 32; off <<= 1) m = fmaxf(m, __shfl_xor(m, off, 64));
        float p = expf(x - m);
        float s = p;
        #pragma unroll
        for (int off = 1; off < 32; off <<= 1) s += __shfl_xor(s, off, 64);
        Apq[tok] = A; kqc[tok] = kap; uq[tok] = -0.5f * A * kap;
        wq[tok]  = p / s;
        ent_out[tok] = ent;
    } else {
        int tt = tok - 4096;
        At[tt] = A; ktc[tt] = kap; vt[tt] = -0.5f * A * kap;
    }
}

// --------------------------------------------------- fused GEMM + vMF epilogue
// 256x256 tile/block, 8 waves in 2x4 quadrants, 8x4 grid of 16x16x32 f16 MFMA.
// 1D grid of 256 blocks with XCD-chunked swizzle (T1): XCD g owns a 4(bx)x8(by)
// rectangle -> per-XCD panel working set 6 MB (vs 16 MB round-robin), so Q/T
// panel re-reads hit the XCD's 4 MiB L2. LDS 128 KB, double-buffered staging,
// one barrier per K-chunk, XOR chunk swizzle for bank-spread ds_read_b128.
// NO tail fusion: round-3 measured per-block device-scope fences (L2
// wb/inv x 256 blocks) at ~65us -- far worse than a 2us kernel launch.
__global__ void __launch_bounds__(512, 2)
gemm_score(const _Float16* __restrict__ Qh, const _Float16* __restrict__ Th,
           const float* __restrict__ Apq, const float* __restrict__ kqc,
           const float* __restrict__ uq,  const float* __restrict__ wq,
           const float* __restrict__ At,  const float* __restrict__ ktc,
           const float* __restrict__ vt,  float* __restrict__ score_out) {
    __shared__ _Float16 Qs[2][256 * 64];   // 2 x 32 KB
    __shared__ _Float16 Ts[2][256 * 64];
    int tid = threadIdx.x;
    int lane = tid & 63, wave = tid >> 6;   // 8 waves
    int wr = wave >> 2, wc = wave & 3;      // 2 (M) x 4 (N)

    // XCD-chunked bijective swizzle: g = bid&7 -> 4x8 rectangle of the 16x16 grid
    int bid = blockIdx.x;
    int g = bid & 7, ii_ = bid >> 3;
    int bx = (g & 3) * 4 + (ii_ & 3);
    int by = (g >> 2) * 8 + (ii_ >> 2);

    floatx4 acc[8][4];
    #pragma unroll
    for (int i = 0; i < 8; ++i)
        #pragma unroll
        for (int j = 0; j < 4; ++j)
            acc[i][j] = (floatx4){0.f, 0.f, 0.f, 0.f};

    int l15 = lane & 15, lq = lane >> 4;
    int swz = l15 & 7;

    // staging: thread covers row rs (+it*64), LDS chunk cl, global chunk cg
    int rs = tid >> 3;                      // 0..63
    int cl = tid & 7;
    int cg = cl ^ (rs & 7);
    const _Float16* gq = Qh + (size_t)(by * 256 + rs) * DDIM + cg * 8;
    const _Float16* gt = Th + (size_t)(bx * 256 + rs) * DDIM + cg * 8;
    int lbase = wave * 1024;                // LDS byte base (+it*8192)

    // prologue: chunk 0 -> buffer 0 (only exposed staging wait in the kernel)
    #pragma unroll
    for (int it = 0; it < 4; ++it) {
        GLOAD_LDS16(gq + it * 64 * DDIM, (char*)Qs[0] + lbase + it * 8192);
        GLOAD_LDS16(gt + it * 64 * DDIM, (char*)Ts[0] + lbase + it * 8192);
    }

    #pragma unroll
    for (int kk = 0; kk < 4; ++kk) {
        int p = kk & 1;
        // drains: chunk-kk loads (issued one iteration ago) + last ds_reads
        __syncthreads();
        if (kk < 3) {                       // prefetch chunk kk+1 into other buf
            #pragma unroll
            for (int it = 0; it < 4; ++it) {
                GLOAD_LDS16(gq + it * 64 * DDIM + (kk + 1) * 64,
                            (char*)Qs[p ^ 1] + lbase + it * 8192);
                GLOAD_LDS16(gt + it * 64 * DDIM + (kk + 1) * 64,
                            (char*)Ts[p ^ 1] + lbase + it * 8192);
            }
        }
        #pragma unroll
        for (int ks = 0; ks < 2; ++ks) {
            half8 a[8], b[4];
            int chunk = (ks * 4 + lq) ^ swz;
            #pragma unroll
            for (int i = 0; i < 8; ++i)
                a[i] = *(const half8*)(Qs[p] + (wr * 128 + i * 16 + l15) * 64 + chunk * 8);
            #pragma unroll
            for (int j = 0; j < 4; ++j)
                b[j] = *(const half8*)(Ts[p] + (wc * 64 + j * 16 + l15) * 64 + chunk * 8);
            #pragma unroll
            for (int i = 0; i < 8; ++i)
                #pragma unroll
                for (int j = 0; j < 4; ++j)
                    acc[i][j] = __builtin_amdgcn_mfma_f32_16x16x32_f16(a[i], b[j], acc[i][j], 0, 0, 0);
        }
    }

    // ---- epilogue: max over 32 t-cols, weighted sum over 32 q-rows
    int colbase = bx * 256 + wc * 64 + l15;
    int rowbase = by * 256 + wr * 128 + lq * 4;
    #pragma unroll
    for (int bi = 0; bi < 4; ++bi) {         // 4 samples per wave (32 rows each)
        #pragma unroll
        for (int bj = 0; bj < 2; ++bj) {     // 2 targets per wave (32 cols each)
            float part = 0.f;
            #pragma unroll
            for (int ii2 = 0; ii2 < 2; ++ii2) {
                int i  = bi * 2 + ii2;
                int rg = rowbase + i * 16;
                float mx[4] = {-INFINITY, -INFINITY, -INFINITY, -INFINITY};
                #pragma unroll
                for (int jj = 0; jj < 2; ++jj) {
                    int j   = bj * 2 + jj;
                    int cg2 = colbase + j * 16;
                    float at_ = At[cg2], kt_ = ktc[cg2], v_ = vt[cg2];
                    floatx4 sim = acc[i][j];
                    #pragma unroll
                    for (int rr = 0; rr < 4; ++rr) {
                        float sc = uq[rg + rr] + v_ +
                                   0.5f * (Apq[rg + rr] * kt_ + at_ * kqc[rg + rr]) * sim[rr];
                        mx[rr] = fmaxf(mx[rr], sc);
                    }
                }
                #pragma unroll
                for (int msk = 1; msk <= 8; msk <<= 1)
                    #pragma unroll
                    for (int rr = 0; rr < 4; ++rr)
                        mx[rr] = fmaxf(mx[rr], __shfl_xor(mx[rr], msk, 64));
                if (l15 == 0) {
                    #pragma unroll
                    for (int rr = 0; rr < 4; ++rr)
                        part += wq[rg + rr] * mx[rr];
                }
            }
            part += __shfl_xor(part, 16, 64);
            part += __shfl_xor(part, 32, 64);
            if (lane == 0) {
                int b = by * 8 + wr * 4 + bi;
                int n = bx * 8 + wc * 2 + bj;
                score_out[b * 128 + n] = part;
            }
        }
    }
}

// ------------------------------------------- logits, log-softmax over n, loss
// One wave per row (16 blocks x 8 waves = 128 rows), coalesced float2 loads,
// shuffle LSE. loss accumulated via atomicAdd (zeroed in prep, stream-ordered).
__global__ void softmax_loss(const float* __restrict__ score, const float* __restrict__ temp_p,
                             float* __restrict__ logits, float* __restrict__ loss) {
    int tid = threadIdx.x, lane = tid & 63, w = tid >> 6;
    int r = blockIdx.x * 8 + w;             // 0..127
    float temp = fmaxf(temp_p[0], 1e-6f);
    float inv = 1.0f / temp;

    float2 v = ((const float2*)(score + r * 128))[lane];
    v.x *= inv; v.y *= inv;
    float m = fmaxf(v.x, v.y);
    #pragma unroll
    for (int off = 1; off < 64; off <<= 1) m = fmaxf(m, __shfl_xor(m, off, 64));
    float e = expf(v.x - m) + expf(v.y - m);
    #pragma unroll
    for (int off = 1; off < 64; off <<= 1) e += __shfl_xor(e, off, 64);
    float lse = m + logf(e);

    ((float2*)(logits + r * 128))[lane] = v;

    if (lane == 0) {
        float le = lse - score[r * 129] * inv;   // diag element
        atomicAdd(loss, le * (1.0f / 128.0f));
    }
}

// ---------------------------------------------------------------------- launch
extern "C" void kernel_launch(void* const* d_in, const int* in_sizes, int n_in,
                              void* d_out, int out_size, void* d_ws, size_t ws_size,
                              hipStream_t stream) {
    const float* q    = (const float*)d_in[0];   // (128,32,256)
    const float* kq   = (const float*)d_in[1];   // (128,32)
    const float* t    = (const float*)d_in[2];   // (128,32,256)
    const float* kt   = (const float*)d_in[3];   // (128,32)
    const float* temp = (const float*)d_in[4];   // scalar

    float* out    = (float*)d_out;
    float* loss   = out;                 // [1]
    float* logits = out + 1;             // [128*128]
    float* score  = out + 1 + 16384;     // [128*128]
    float* ent    = out + 1 + 32768;     // [128*32]

    char* ws = (char*)d_ws;
    _Float16* Qh = (_Float16*)(ws);
    _Float16* Th = (_Float16*)(ws + (1 << 21));
    float* stats = (float*)(ws + (1 << 22));
    float *Apq = stats,          *kqc = stats + 4096, *uq = stats + 8192,
          *wq  = stats + 12288,  *At  = stats + 16384, *ktc = stats + 20480,
          *vt  = stats + 24576;

    prep<<<2080, 256, 0, stream>>>(q, t, Qh, Th, kq, kt,
                                   Apq, kqc, uq, wq, At, ktc, vt, ent, loss);
    gemm_score<<<256, 512, 0, stream>>>(Qh, Th, Apq, kqc, uq, wq, At, ktc, vt, score);
    softmax_loss<<<16, 512, 0, stream>>>(score, temp, logits, loss);
}